// Round 18
// baseline (2629.156 us; speedup 1.0000x reference)
//
#include <hip/hip_runtime.h>

#define DECAY 0.99f
#define OMD   0.01f
#define EPS   1e-5f

constexpr int Bb = 16, Ss = 2048, Dd = 512, Kk = 2048;
constexpr int Nn = Bb * Ss;  // 32768
constexpr int RP = 1088;     // padded interleaved row: 1088 elems = 17*128B

typedef __attribute__((ext_vector_type(8))) short short8;
typedef __attribute__((ext_vector_type(4))) float f32x4;

__device__ __forceinline__ unsigned short f2bf(float x) {
    unsigned u = __float_as_uint(x);
    unsigned r = (u + 0x7FFFu + ((u >> 16) & 1u)) >> 16;   // RN-even
    return (unsigned short)r;
}
__device__ __forceinline__ float bf2f(unsigned short u) {
    return __uint_as_float((unsigned)u << 16);
}

__device__ __forceinline__ void gload_lds16(const void* g, void* l) {
    __builtin_amdgcn_global_load_lds(
        (const __attribute__((address_space(1))) void*)g,
        (__attribute__((address_space(3))) void*)l, 16, 0, 0);
}

// pair-swap the u16 lanes of each dword: [h0 m0 h1 m1 ...] -> [m0 h0 m1 h1 ...]
__device__ __forceinline__ short8 swap16(short8 v) {
    union { short8 s; unsigned u[4]; } a, b;
    a.s = v;
    #pragma unroll
    for (int i = 0; i < 4; ++i) b.u[i] = (a.u[i] >> 16) | (a.u[i] << 16);
    return b.s;
}

#define BARRIER() do { asm volatile("" ::: "memory"); \
                       __builtin_amdgcn_s_barrier();  \
                       asm volatile("" ::: "memory"); } while (0)

// ---------------- row sum-of-squares (fallback path only) -------------------
__global__ void rows_sq(const float* __restrict__ in, float* __restrict__ out, int nrows) {
    int row  = blockIdx.x * 4 + (threadIdx.x >> 6);
    int lane = threadIdx.x & 63;
    if (row >= nrows) return;
    const float4* p = (const float4*)(in + (size_t)row * Dd);
    float s = 0.f;
    #pragma unroll
    for (int i = 0; i < 2; ++i) {
        float4 v = p[lane + 64 * i];
        s += v.x * v.x + v.y * v.y + v.z * v.z + v.w * v.w;
    }
    #pragma unroll
    for (int off = 32; off; off >>= 1) s += __shfl_down(s, off);
    if (lane == 0) out[row] = s;
}

// ------- fused: fp32 -> k-interleaved bf16 (h,m) plane + row sum-of-squares -
__global__ void conv_ilv(const float* __restrict__ in,
                         unsigned short* __restrict__ out,
                         float* __restrict__ sq) {
    int row  = blockIdx.x * 4 + (threadIdx.x >> 6);
    int lane = threadIdx.x & 63;
    const float4* p = (const float4*)(in + (size_t)row * Dd);
    uint4* o = (uint4*)(out + (size_t)row * RP);
    float s = 0.f;
    #pragma unroll
    for (int i = 0; i < 2; ++i) {
        int idx = lane + 64 * i;
        float4 v = p[idx];
        float f[4] = {v.x, v.y, v.z, v.w};
        unsigned d[4];
        #pragma unroll
        for (int j = 0; j < 4; ++j) {
            float x = f[j];
            s += x * x;
            unsigned short h = f2bf(x);
            unsigned short m = f2bf(x - bf2f(h));
            d[j] = ((unsigned)m << 16) | h;
        }
        o[idx] = make_uint4(d[0], d[1], d[2], d[3]);
    }
    #pragma unroll
    for (int off = 32; off; off >>= 1) s += __shfl_down(s, off);
    if (lane == 0) sq[row] = s;
}

// -------- bf16x2 4-term GEMM, 256x256, SINGLE-buffer LDS, 2 blocks/CU ------
// Same math/swizzle as the proven 291-us dbuf kernel; LDS halved to 64 KB so
// TWO blocks co-reside per CU (m114 TLP-overlap: block A's vmcnt(0) stage
// drain overlaps block B's MFMA burst at the CU scheduler level).
// Per tile: stage (8 gloads) -> vmcnt(0)+barrier -> compute -> barrier.
__global__ __launch_bounds__(512, 4) void gemm_ilv(
    const unsigned short* __restrict__ xhm,  // [Nn][RP] interleaved (h,m)
    const unsigned short* __restrict__ ehm,  // [Kk][RP]
    const float* __restrict__ xsq,
    const float* __restrict__ esq,
    float* __restrict__ dist,                // [Nn, Kk]
    unsigned long long* __restrict__ packed) // [Nn] argmax accumulator
{
    __shared__ unsigned short As[256][64];   // 32 KB
    __shared__ unsigned short Bs[256][64];   // 32 KB  -> 64 KB total

    const int tid  = threadIdx.x;
    const int lane = tid & 63;
    const int wid  = tid >> 6;
    const int wr   = wid >> 2;   // 0..1  (M, 128 rows each)
    const int wc   = wid & 3;    // 0..3  (N, 64 cols each)

    // XCD-aware swizzle (nwg = 1024, divisible by 8 -> bijective)
    int bid = blockIdx.x;
    int wg  = (bid & 7) * 128 + (bid >> 3);
    int mb  = wg >> 3, nb = wg & 7;
    const int row0 = mb * 256, col0 = nb * 256;

    f32x4 acc[8][4] = {};

    const int l8   = lane >> 3;          // 0..7
    const int csrc = (lane & 7) ^ l8;    // pre-swizzled source chunk

    // stage one 256x64-elem interleaved tile (32 KB): 4 gloads/thread
    auto stageT = [&](const unsigned short* pl, unsigned short (*dst)[64],
                      int base, int t) {
        #pragma unroll
        for (int jj = 0; jj < 4; ++jj) {
            int rowbase = jj * 64 + wid * 8;
            int row = rowbase + l8;
            const unsigned short* src =
                pl + (size_t)(base + row) * RP + t * 64 + csrc * 8;
            gload_lds16(src, &dst[rowbase][0]);
        }
    };

    auto readA = [&](int g, short8* out) {   // 8 m-frags for kgroup g
        #pragma unroll
        for (int m = 0; m < 8; ++m) {
            int r = wr * 128 + m * 16 + (lane & 15);
            int c = (g * 4 + (lane >> 4)) ^ (r & 7);
            out[m] = *(const short8*)&As[r][c * 8];
        }
    };
    auto readB = [&](int g, short8* out) {   // 4 n-frags for kgroup g
        #pragma unroll
        for (int n = 0; n < 4; ++n) {
            int r = wc * 64 + n * 16 + (lane & 15);
            int c = (g * 4 + (lane >> 4)) ^ (r & 7);
            out[n] = *(const short8*)&Bs[r][c * 8];
        }
    };

    for (int t = 0; t < 16; ++t) {
        stageT(xhm, As, row0, t);
        stageT(ehm, Bs, col0, t);
        asm volatile("s_waitcnt vmcnt(0)" ::: "memory");
        BARRIER();

        #pragma unroll
        for (int g = 0; g < 2; ++g) {
            short8 va[8], vb[4], vb2[4];
            readA(g, va);
            readB(g, vb);
            #pragma unroll
            for (int n = 0; n < 4; ++n) vb2[n] = swap16(vb[n]);
            #pragma unroll
            for (int m = 0; m < 8; ++m)
                #pragma unroll
                for (int n = 0; n < 4; ++n)
                    acc[m][n] = __builtin_amdgcn_mfma_f32_16x16x32_bf16(
                        va[m], vb[n], acc[m][n], 0, 0, 0);   // hh + mm
            #pragma unroll
            for (int m = 0; m < 8; ++m)
                #pragma unroll
                for (int n = 0; n < 4; ++n)
                    acc[m][n] = __builtin_amdgcn_mfma_f32_16x16x32_bf16(
                        va[m], vb2[n], acc[m][n], 0, 0, 0);  // hm + mh
        }

        BARRIER();   // all reads done before next tile's stage overwrites
    }

    // epilogue: dist = 2*dot - xsq - esq ; fused per-row argmax
    const int jrow = (lane >> 4) * 4;
    const int ncol = lane & 15;
    #pragma unroll
    for (int m = 0; m < 8; ++m) {
        int rbase = row0 + wr * 128 + m * 16 + jrow;
        #pragma unroll
        for (int j = 0; j < 4; ++j) {
            int row = rbase + j;
            float xs = xsq[row];
            float best = -3.4e38f; int bi = 0;
            #pragma unroll
            for (int n = 0; n < 4; ++n) {
                int col = col0 + wc * 64 + n * 16 + ncol;
                float v = 2.f * acc[m][n][j] - xs - esq[col];
                dist[(size_t)row * Kk + col] = v;
                if (v > best) { best = v; bi = col; }
            }
            unsigned u = __float_as_uint(best);
            u = (u & 0x80000000u) ? ~u : (u | 0x80000000u);
            unsigned long long pk = ((unsigned long long)u << 32) | (unsigned)(~bi);
            #pragma unroll
            for (int off = 1; off < 16; off <<= 1) {
                unsigned long long o = __shfl_xor(pk, off);
                if (o > pk) pk = o;
            }
            if (ncol == 0) atomicMax(&packed[row], pk);
        }
    }
}

// ---------------- gather/scatter fused with argmax unpack ------------------
// 256 threads; scalar per-lane atomics at stride-1 addresses (coalesced).
__global__ void gather_scatter_packed(const float* __restrict__ x,
                                      const float* __restrict__ embed,
                                      const unsigned long long* __restrict__ packed,
                                      float* __restrict__ quant,
                                      float* __restrict__ ind_f,
                                      float* __restrict__ esum,
                                      int* __restrict__ bins) {
    int n = blockIdx.x;
    int k = (int)(~(unsigned)(packed[n] & 0xFFFFFFFFull));
    int t = threadIdx.x;
    size_t xb = (size_t)n * Dd;
    size_t eb = (size_t)k * Dd;
    float v0 = x[xb + t];
    float v1 = x[xb + t + 256];
    quant[xb + t]       = embed[eb + t];
    quant[xb + t + 256] = embed[eb + t + 256];
    atomicAdd(&esum[eb + t],       v0);
    atomicAdd(&esum[eb + t + 256], v1);
    if (t == 0) { ind_f[n] = (float)k; atomicAdd(&bins[k], 1); }
}

// ---------------- OLD fp32 GEMM + helpers (fallback when ws too small) -----
#define BM 64
#define BN 64
#define BK 32
__global__ __launch_bounds__(256) void gemm_dist(
    const float* __restrict__ A, const float* __restrict__ Bm_,
    const float* __restrict__ xsq, const float* __restrict__ esq,
    float* __restrict__ dist)
{
    __shared__ float Asl[BK][BM + 4];
    __shared__ float Bsl[BK][BN + 4];
    int tid = threadIdx.x;
    int row0 = blockIdx.x * BM, col0 = blockIdx.y * BN;
    int tx = tid & 15, ty = tid >> 4;
    float acc[4][4] = {};
    int lr = tid >> 3, lc = (tid & 7) * 4;
    for (int d0 = 0; d0 < Dd; d0 += BK) {
        float4 a0 = *(const float4*)(A   + (size_t)(row0 + lr)      * Dd + d0 + lc);
        float4 a1 = *(const float4*)(A   + (size_t)(row0 + lr + 32) * Dd + d0 + lc);
        float4 b0 = *(const float4*)(Bm_ + (size_t)(col0 + lr)      * Dd + d0 + lc);
        float4 b1 = *(const float4*)(Bm_ + (size_t)(col0 + lr + 32) * Dd + d0 + lc);
        __syncthreads();
        Asl[lc + 0][lr] = a0.x; Asl[lc + 1][lr] = a0.y; Asl[lc + 2][lr] = a0.z; Asl[lc + 3][lr] = a0.w;
        Asl[lc + 0][lr + 32] = a1.x; Asl[lc + 1][lr + 32] = a1.y; Asl[lc + 2][lr + 32] = a1.z; Asl[lc + 3][lr + 32] = a1.w;
        Bsl[lc + 0][lr] = b0.x; Bsl[lc + 1][lr] = b0.y; Bsl[lc + 2][lr] = b0.z; Bsl[lc + 3][lr] = b0.w;
        Bsl[lc + 0][lr + 32] = b1.x; Bsl[lc + 1][lr + 32] = b1.y; Bsl[lc + 2][lr + 32] = b1.z; Bsl[lc + 3][lr + 32] = b1.w;
        __syncthreads();
        #pragma unroll
        for (int kd = 0; kd < BK; ++kd) {
            float4 av = *(const float4*)&Asl[kd][ty * 4];
            float4 bv = *(const float4*)&Bsl[kd][tx * 4];
            float a[4] = {av.x, av.y, av.z, av.w};
            float b[4] = {bv.x, bv.y, bv.z, bv.w};
            #pragma unroll
            for (int i = 0; i < 4; ++i)
                #pragma unroll
                for (int j = 0; j < 4; ++j)
                    acc[i][j] = fmaf(a[i], b[j], acc[i][j]);
        }
    }
    #pragma unroll
    for (int i = 0; i < 4; ++i) {
        int row = row0 + ty * 4 + i;
        float xs = xsq[row];
        float4 o;
        int col = col0 + tx * 4;
        o.x = 2.f * acc[i][0] - xs - esq[col + 0];
        o.y = 2.f * acc[i][1] - xs - esq[col + 1];
        o.z = 2.f * acc[i][2] - xs - esq[col + 2];
        o.w = 2.f * acc[i][3] - xs - esq[col + 3];
        *(float4*)(dist + (size_t)row * Kk + col) = o;
    }
}

__global__ void argmax_k(const float* __restrict__ dist,
                         float* __restrict__ ind_f, int* __restrict__ ind_i) {
    int row  = blockIdx.x * 4 + (threadIdx.x >> 6);
    int lane = threadIdx.x & 63;
    const float4* p = (const float4*)(dist + (size_t)row * Kk);
    float best = -3.4e38f;
    int bidx = 0;
    #pragma unroll
    for (int it = 0; it < Kk / 4 / 64; ++it) {
        int i = lane + it * 64;
        float4 v = p[i];
        int base = i * 4;
        if (v.x > best) { best = v.x; bidx = base + 0; }
        if (v.y > best) { best = v.y; bidx = base + 1; }
        if (v.z > best) { best = v.z; bidx = base + 2; }
        if (v.w > best) { best = v.w; bidx = base + 3; }
    }
    #pragma unroll
    for (int off = 32; off; off >>= 1) {
        float ov = __shfl_down(best, off);
        int   oi = __shfl_down(bidx, off);
        if (ov > best || (ov == best && oi < bidx)) { best = ov; bidx = oi; }
    }
    if (lane == 0) { ind_f[row] = (float)bidx; ind_i[row] = bidx; }
}

__global__ void gather_scatter(const float* __restrict__ x,
                               const float* __restrict__ embed,
                               const int* __restrict__ ind,
                               float* __restrict__ quant,
                               float* __restrict__ esum,
                               int* __restrict__ bins) {
    int n = blockIdx.x;
    int k = ind[n];
    int t = threadIdx.x;
    size_t xb = (size_t)n * Dd;
    size_t eb = (size_t)k * Dd;
    float v0 = x[xb + t];
    float v1 = x[xb + t + 256];
    quant[xb + t]       = embed[eb + t];
    quant[xb + t + 256] = embed[eb + t + 256];
    atomicAdd(&esum[eb + t],       v0);
    atomicAdd(&esum[eb + t + 256], v1);
    if (t == 0) atomicAdd(&bins[k], 1);
}

// ---------------- EMA cluster size + laplace total -------------------------
__global__ void finalize1(const float* __restrict__ cs, const int* __restrict__ bins,
                          float* __restrict__ ncs, float* __restrict__ total_ws) {
    __shared__ float red[16];
    int t = threadIdx.x;
    float s = 0.f;
    for (int k = t; k < Kk; k += 1024) {
        float v = cs[k] * DECAY + OMD * (float)bins[k];
        ncs[k] = v;
        s += v;
    }
    #pragma unroll
    for (int off = 32; off; off >>= 1) s += __shfl_down(s, off);
    if ((t & 63) == 0) red[t >> 6] = s;
    __syncthreads();
    if (t == 0) {
        float tot = 0.f;
        #pragma unroll
        for (int i = 0; i < 16; ++i) tot += red[i];
        total_ws[0] = tot;
    }
}

// ---------------- EMA embed_avg + smoothed divide ---------------------------
__global__ void finalize2(const float* __restrict__ ea, const float* __restrict__ esum,
                          const float* __restrict__ ncs, const float* __restrict__ total_ws,
                          float* __restrict__ nea, float* __restrict__ ne) {
    int idx = blockIdx.x * 256 + threadIdx.x;
    float total = total_ws[0];
    int k = idx >> 7;
    float sm = (ncs[k] + EPS) / (total + Kk * EPS) * total;
    float inv = 1.f / sm;
    float4 a = ((const float4*)ea)[idx];
    float4 s = ((const float4*)esum)[idx];
    float4 r;
    r.x = a.x * DECAY + OMD * s.x;
    r.y = a.y * DECAY + OMD * s.y;
    r.z = a.z * DECAY + OMD * s.z;
    r.w = a.w * DECAY + OMD * s.w;
    ((float4*)nea)[idx] = r;
    float4 e;
    e.x = r.x * inv; e.y = r.y * inv; e.z = r.z * inv; e.w = r.w * inv;
    ((float4*)ne)[idx] = e;
}

extern "C" void kernel_launch(void* const* d_in, const int* in_sizes, int n_in,
                              void* d_out, int out_size, void* d_ws, size_t ws_size,
                              hipStream_t stream) {
    const float* x     = (const float*)d_in[0];
    const float* embed = (const float*)d_in[1];
    const float* cs    = (const float*)d_in[2];
    const float* ea    = (const float*)d_in[3];

    float* out     = (float*)d_out;
    float* o_quant = out;
    float* o_ind   = o_quant + (size_t)Nn * Dd;
    float* o_dist  = o_ind + Nn;
    float* o_ncs   = o_dist + (size_t)Nn * Kk;
    float* o_nea   = o_ncs + Kk;
    float* o_ne    = o_nea + (size_t)Kk * Dd;

    // ---- ws layout (regions sized for 3 planes; padded-ilv uses ~2.1-worth) --
    size_t xp_elems = (size_t)3 * Nn * Dd;       // bf16 capacity (>= Nn*RP)
    size_t ep_elems = (size_t)3 * Kk * Dd;       // >= Kk*RP
    char* w = (char*)d_ws;
    unsigned short* xp = (unsigned short*)w;                 w += xp_elems * 2;
    unsigned short* epp = (unsigned short*)w;                w += ep_elems * 2;
    float* xsq   = (float*)w;                                w += (size_t)Nn * 4;
    float* esq   = (float*)w;                                w += (size_t)Kk * 4;
    int*   ind_i = (int*)w;                                  w += (size_t)Nn * 4;
    int*   bins  = (int*)w;                                  w += (size_t)Kk * 4;
    float* esum  = (float*)w;                                w += (size_t)Kk * Dd * 4;
    unsigned long long* packed = (unsigned long long*)w;     w += (size_t)Nn * 8;
    float* total = (float*)w;                                w += 256;
    size_t need = (size_t)(w - (char*)d_ws);

    if (ws_size >= need) {
        hipMemsetAsync(bins, 0, (size_t)Kk * 4 + (size_t)Kk * Dd * 4 + (size_t)Nn * 8, stream);

        conv_ilv<<<Nn / 4, 256, 0, stream>>>(x, xp, xsq);
        conv_ilv<<<Kk / 4, 256, 0, stream>>>(embed, epp, esq);

        gemm_ilv<<<(Nn / 256) * (Kk / 256), 512, 0, stream>>>(
            xp, epp, xsq, esq, o_dist, packed);

        gather_scatter_packed<<<Nn, 256, 0, stream>>>(
            x, embed, packed, o_quant, o_ind, esum, bins);
    } else {
        float* fxsq  = (float*)d_ws;
        float* fesq  = fxsq + Nn;
        int*   find  = (int*)(fesq + Kk);
        int*   fbins = find + Nn;
        float* fesum = (float*)(fbins + Kk);
        float* ftot  = fesum + (size_t)Kk * Dd;
        xsq = fxsq; esq = fesq; ind_i = find; bins = fbins; esum = fesum; total = ftot;

        hipMemsetAsync(bins, 0, (size_t)(Kk + Kk * Dd) * sizeof(float), stream);
        rows_sq<<<Nn / 4, 256, 0, stream>>>(x, xsq, Nn);
        rows_sq<<<Kk / 4, 256, 0, stream>>>(embed, esq, Kk);
        dim3 g(Nn / BM, Kk / BN);
        gemm_dist<<<g, 256, 0, stream>>>(x, embed, xsq, esq, o_dist);
        argmax_k<<<Nn / 4, 256, 0, stream>>>(o_dist, o_ind, ind_i);
        gather_scatter<<<Nn, 256, 0, stream>>>(x, embed, ind_i, o_quant, esum, bins);
    }

    finalize1<<<1, 1024, 0, stream>>>(cs, bins, o_ncs, total);
    finalize2<<<(Kk * Dd / 4) / 256, 256, 0, stream>>>(ea, esum, o_ncs, total, o_nea, o_ne);
}

// Round 19
// 389.105 us; speedup vs baseline: 6.7569x; 6.7569x over previous
//
#include <hip/hip_runtime.h>

#define DECAY 0.99f
#define OMD   0.01f
#define EPS   1e-5f

constexpr int Bb = 16, Ss = 2048, Dd = 512, Kk = 2048;
constexpr int Nn = Bb * Ss;  // 32768
constexpr int RP = 1088;     // padded interleaved row: 1088 elems = 17*128B

typedef __attribute__((ext_vector_type(8))) short short8;
typedef __attribute__((ext_vector_type(4))) float f32x4;

__device__ __forceinline__ unsigned short f2bf(float x) {
    unsigned u = __float_as_uint(x);
    unsigned r = (u + 0x7FFFu + ((u >> 16) & 1u)) >> 16;   // RN-even
    return (unsigned short)r;
}
__device__ __forceinline__ float bf2f(unsigned short u) {
    return __uint_as_float((unsigned)u << 16);
}

__device__ __forceinline__ void gload_lds16(const void* g, void* l) {
    __builtin_amdgcn_global_load_lds(
        (const __attribute__((address_space(1))) void*)g,
        (__attribute__((address_space(3))) void*)l, 16, 0, 0);
}

// pair-swap the u16 lanes of each dword: [h0 m0 h1 m1 ...] -> [m0 h0 m1 h1 ...]
__device__ __forceinline__ short8 swap16(short8 v) {
    union { short8 s; unsigned u[4]; } a, b;
    a.s = v;
    #pragma unroll
    for (int i = 0; i < 4; ++i) b.u[i] = (a.u[i] >> 16) | (a.u[i] << 16);
    return b.s;
}

#define BARRIER() do { asm volatile("" ::: "memory"); \
                       __builtin_amdgcn_s_barrier();  \
                       asm volatile("" ::: "memory"); } while (0)

// ---------------- row sum-of-squares (fallback path only) -------------------
__global__ void rows_sq(const float* __restrict__ in, float* __restrict__ out, int nrows) {
    int row  = blockIdx.x * 4 + (threadIdx.x >> 6);
    int lane = threadIdx.x & 63;
    if (row >= nrows) return;
    const float4* p = (const float4*)(in + (size_t)row * Dd);
    float s = 0.f;
    #pragma unroll
    for (int i = 0; i < 2; ++i) {
        float4 v = p[lane + 64 * i];
        s += v.x * v.x + v.y * v.y + v.z * v.z + v.w * v.w;
    }
    #pragma unroll
    for (int off = 32; off; off >>= 1) s += __shfl_down(s, off);
    if (lane == 0) out[row] = s;
}

// ------- fused: fp32 -> k-interleaved bf16 (h,m) plane + row sum-of-squares -
__global__ void conv_ilv(const float* __restrict__ in,
                         unsigned short* __restrict__ out,
                         float* __restrict__ sq) {
    int row  = blockIdx.x * 4 + (threadIdx.x >> 6);
    int lane = threadIdx.x & 63;
    const float4* p = (const float4*)(in + (size_t)row * Dd);
    uint4* o = (uint4*)(out + (size_t)row * RP);
    float s = 0.f;
    #pragma unroll
    for (int i = 0; i < 2; ++i) {
        int idx = lane + 64 * i;
        float4 v = p[idx];
        float f[4] = {v.x, v.y, v.z, v.w};
        unsigned d[4];
        #pragma unroll
        for (int j = 0; j < 4; ++j) {
            float x = f[j];
            s += x * x;
            unsigned short h = f2bf(x);
            unsigned short m = f2bf(x - bf2f(h));
            d[j] = ((unsigned)m << 16) | h;
        }
        o[idx] = make_uint4(d[0], d[1], d[2], d[3]);
    }
    #pragma unroll
    for (int off = 32; off; off >>= 1) s += __shfl_down(s, off);
    if (lane == 0) sq[row] = s;
}

// -------- bf16x2 4-term GEMM via k-interleaved planes, 256x256, dbuf -------
// (Best-measured configuration: 291 us, 0 bank conflicts, MfmaUtil 42%.)
// One raw K-tile (32 cols) = 64 interleaved elems = 128B contiguous per row.
// dot(a', b')  = hh + mm ;  dot(a', swap16(b')) = hm + mh  -> all 4 terms,
// one staged copy of each operand. 16 raw tiles; stage-first into dead
// buffer, single vmcnt(0)+barrier per tile; 128B-row XOR-(r&7) swizzle
// (both-sides) = zero bank conflicts. 8 waves (2M x 4N). 1 block/CU (the
// 256^2 tile's 128-reg accumulator makes 2 blocks/CU spill — r18 evidence).
__global__ __launch_bounds__(512, 1) void gemm_ilv(
    const unsigned short* __restrict__ xhm,  // [Nn][RP] interleaved (h,m)
    const unsigned short* __restrict__ ehm,  // [Kk][RP]
    const float* __restrict__ xsq,
    const float* __restrict__ esq,
    float* __restrict__ dist,                // [Nn, Kk]
    unsigned long long* __restrict__ packed) // [Nn] argmax accumulator
{
    __shared__ unsigned short As[2][256][64];   // 64 KB
    __shared__ unsigned short Bs[2][256][64];   // 64 KB

    const int tid  = threadIdx.x;
    const int lane = tid & 63;
    const int wid  = tid >> 6;
    const int wr   = wid >> 2;   // 0..1  (M, 128 rows each)
    const int wc   = wid & 3;    // 0..3  (N, 64 cols each)

    // XCD-aware swizzle (nwg = 1024, divisible by 8 -> bijective)
    int bid = blockIdx.x;
    int wg  = (bid & 7) * 128 + (bid >> 3);
    int mb  = wg >> 3, nb = wg & 7;
    const int row0 = mb * 256, col0 = nb * 256;

    f32x4 acc[8][4] = {};

    const int l8   = lane >> 3;          // 0..7
    const int csrc = (lane & 7) ^ l8;    // pre-swizzled source chunk

    // stage one 256x64-elem interleaved tile (32 KB): 4 gloads/thread
    auto stageT = [&](const unsigned short* pl, unsigned short (*dst)[64],
                      int base, int t) {
        #pragma unroll
        for (int jj = 0; jj < 4; ++jj) {
            int rowbase = jj * 64 + wid * 8;
            int row = rowbase + l8;
            const unsigned short* src =
                pl + (size_t)(base + row) * RP + t * 64 + csrc * 8;
            gload_lds16(src, &dst[rowbase][0]);
        }
    };

    auto readA = [&](int d, int g, short8* out) {   // 8 m-frags for kgroup g
        #pragma unroll
        for (int m = 0; m < 8; ++m) {
            int r = wr * 128 + m * 16 + (lane & 15);
            int c = (g * 4 + (lane >> 4)) ^ (r & 7);
            out[m] = *(const short8*)&As[d][r][c * 8];
        }
    };
    auto readB = [&](int d, int g, short8* out) {   // 4 n-frags for kgroup g
        #pragma unroll
        for (int n = 0; n < 4; ++n) {
            int r = wc * 64 + n * 16 + (lane & 15);
            int c = (g * 4 + (lane >> 4)) ^ (r & 7);
            out[n] = *(const short8*)&Bs[d][r][c * 8];
        }
    };

    // prologue: stage tile 0 into slot 0
    stageT(xhm, As[0], row0, 0);
    stageT(ehm, Bs[0], col0, 0);
    asm volatile("s_waitcnt vmcnt(0)" ::: "memory");
    BARRIER();

    for (int t = 0; t < 16; ++t) {
        const int cur = t & 1, nxt = cur ^ 1;
        if (t < 15) {
            stageT(xhm, As[nxt], row0, t + 1);
            stageT(ehm, Bs[nxt], col0, t + 1);
        }

        #pragma unroll
        for (int g = 0; g < 2; ++g) {
            short8 va[8], vb[4], vb2[4];
            readA(cur, g, va);
            readB(cur, g, vb);
            #pragma unroll
            for (int n = 0; n < 4; ++n) vb2[n] = swap16(vb[n]);
            #pragma unroll
            for (int m = 0; m < 8; ++m)
                #pragma unroll
                for (int n = 0; n < 4; ++n)
                    acc[m][n] = __builtin_amdgcn_mfma_f32_16x16x32_bf16(
                        va[m], vb[n], acc[m][n], 0, 0, 0);   // hh + mm
            #pragma unroll
            for (int m = 0; m < 8; ++m)
                #pragma unroll
                for (int n = 0; n < 4; ++n)
                    acc[m][n] = __builtin_amdgcn_mfma_f32_16x16x32_bf16(
                        va[m], vb2[n], acc[m][n], 0, 0, 0);  // hm + mh
        }

        asm volatile("s_waitcnt vmcnt(0)" ::: "memory");
        BARRIER();
    }

    // epilogue: dist = 2*dot - xsq - esq ; fused per-row argmax
    const int jrow = (lane >> 4) * 4;
    const int ncol = lane & 15;
    #pragma unroll
    for (int m = 0; m < 8; ++m) {
        int rbase = row0 + wr * 128 + m * 16 + jrow;
        #pragma unroll
        for (int j = 0; j < 4; ++j) {
            int row = rbase + j;
            float xs = xsq[row];
            float best = -3.4e38f; int bi = 0;
            #pragma unroll
            for (int n = 0; n < 4; ++n) {
                int col = col0 + wc * 64 + n * 16 + ncol;
                float v = 2.f * acc[m][n][j] - xs - esq[col];
                dist[(size_t)row * Kk + col] = v;
                if (v > best) { best = v; bi = col; }
            }
            unsigned u = __float_as_uint(best);
            u = (u & 0x80000000u) ? ~u : (u | 0x80000000u);
            unsigned long long pk = ((unsigned long long)u << 32) | (unsigned)(~bi);
            #pragma unroll
            for (int off = 1; off < 16; off <<= 1) {
                unsigned long long o = __shfl_xor(pk, off);
                if (o > pk) pk = o;
            }
            if (ncol == 0) atomicMax(&packed[row], pk);
        }
    }
}

// ---------------- gather/scatter fused with argmax unpack ------------------
// 256 threads; scalar per-lane atomics at stride-1 addresses (coalesced).
__global__ void gather_scatter_packed(const float* __restrict__ x,
                                      const float* __restrict__ embed,
                                      const unsigned long long* __restrict__ packed,
                                      float* __restrict__ quant,
                                      float* __restrict__ ind_f,
                                      float* __restrict__ esum,
                                      int* __restrict__ bins) {
    int n = blockIdx.x;
    int k = (int)(~(unsigned)(packed[n] & 0xFFFFFFFFull));
    int t = threadIdx.x;
    size_t xb = (size_t)n * Dd;
    size_t eb = (size_t)k * Dd;
    float v0 = x[xb + t];
    float v1 = x[xb + t + 256];
    quant[xb + t]       = embed[eb + t];
    quant[xb + t + 256] = embed[eb + t + 256];
    atomicAdd(&esum[eb + t],       v0);
    atomicAdd(&esum[eb + t + 256], v1);
    if (t == 0) { ind_f[n] = (float)k; atomicAdd(&bins[k], 1); }
}

// ---------------- OLD fp32 GEMM + helpers (fallback when ws too small) -----
#define BM 64
#define BN 64
#define BK 32
__global__ __launch_bounds__(256) void gemm_dist(
    const float* __restrict__ A, const float* __restrict__ Bm_,
    const float* __restrict__ xsq, const float* __restrict__ esq,
    float* __restrict__ dist)
{
    __shared__ float Asl[BK][BM + 4];
    __shared__ float Bsl[BK][BN + 4];
    int tid = threadIdx.x;
    int row0 = blockIdx.x * BM, col0 = blockIdx.y * BN;
    int tx = tid & 15, ty = tid >> 4;
    float acc[4][4] = {};
    int lr = tid >> 3, lc = (tid & 7) * 4;
    for (int d0 = 0; d0 < Dd; d0 += BK) {
        float4 a0 = *(const float4*)(A   + (size_t)(row0 + lr)      * Dd + d0 + lc);
        float4 a1 = *(const float4*)(A   + (size_t)(row0 + lr + 32) * Dd + d0 + lc);
        float4 b0 = *(const float4*)(Bm_ + (size_t)(col0 + lr)      * Dd + d0 + lc);
        float4 b1 = *(const float4*)(Bm_ + (size_t)(col0 + lr + 32) * Dd + d0 + lc);
        __syncthreads();
        Asl[lc + 0][lr] = a0.x; Asl[lc + 1][lr] = a0.y; Asl[lc + 2][lr] = a0.z; Asl[lc + 3][lr] = a0.w;
        Asl[lc + 0][lr + 32] = a1.x; Asl[lc + 1][lr + 32] = a1.y; Asl[lc + 2][lr + 32] = a1.z; Asl[lc + 3][lr + 32] = a1.w;
        Bsl[lc + 0][lr] = b0.x; Bsl[lc + 1][lr] = b0.y; Bsl[lc + 2][lr] = b0.z; Bsl[lc + 3][lr] = b0.w;
        Bsl[lc + 0][lr + 32] = b1.x; Bsl[lc + 1][lr + 32] = b1.y; Bsl[lc + 2][lr + 32] = b1.z; Bsl[lc + 3][lr + 32] = b1.w;
        __syncthreads();
        #pragma unroll
        for (int kd = 0; kd < BK; ++kd) {
            float4 av = *(const float4*)&Asl[kd][ty * 4];
            float4 bv = *(const float4*)&Bsl[kd][tx * 4];
            float a[4] = {av.x, av.y, av.z, av.w};
            float b[4] = {bv.x, bv.y, bv.z, bv.w};
            #pragma unroll
            for (int i = 0; i < 4; ++i)
                #pragma unroll
                for (int j = 0; j < 4; ++j)
                    acc[i][j] = fmaf(a[i], b[j], acc[i][j]);
        }
    }
    #pragma unroll
    for (int i = 0; i < 4; ++i) {
        int row = row0 + ty * 4 + i;
        float xs = xsq[row];
        float4 o;
        int col = col0 + tx * 4;
        o.x = 2.f * acc[i][0] - xs - esq[col + 0];
        o.y = 2.f * acc[i][1] - xs - esq[col + 1];
        o.z = 2.f * acc[i][2] - xs - esq[col + 2];
        o.w = 2.f * acc[i][3] - xs - esq[col + 3];
        *(float4*)(dist + (size_t)row * Kk + col) = o;
    }
}

__global__ void argmax_k(const float* __restrict__ dist,
                         float* __restrict__ ind_f, int* __restrict__ ind_i) {
    int row  = blockIdx.x * 4 + (threadIdx.x >> 6);
    int lane = threadIdx.x & 63;
    const float4* p = (const float4*)(dist + (size_t)row * Kk);
    float best = -3.4e38f;
    int bidx = 0;
    #pragma unroll
    for (int it = 0; it < Kk / 4 / 64; ++it) {
        int i = lane + it * 64;
        float4 v = p[i];
        int base = i * 4;
        if (v.x > best) { best = v.x; bidx = base + 0; }
        if (v.y > best) { best = v.y; bidx = base + 1; }
        if (v.z > best) { best = v.z; bidx = base + 2; }
        if (v.w > best) { best = v.w; bidx = base + 3; }
    }
    #pragma unroll
    for (int off = 32; off; off >>= 1) {
        float ov = __shfl_down(best, off);
        int   oi = __shfl_down(bidx, off);
        if (ov > best || (ov == best && oi < bidx)) { best = ov; bidx = oi; }
    }
    if (lane == 0) { ind_f[row] = (float)bidx; ind_i[row] = bidx; }
}

__global__ void gather_scatter(const float* __restrict__ x,
                               const float* __restrict__ embed,
                               const int* __restrict__ ind,
                               float* __restrict__ quant,
                               float* __restrict__ esum,
                               int* __restrict__ bins) {
    int n = blockIdx.x;
    int k = ind[n];
    int t = threadIdx.x;
    size_t xb = (size_t)n * Dd;
    size_t eb = (size_t)k * Dd;
    float v0 = x[xb + t];
    float v1 = x[xb + t + 256];
    quant[xb + t]       = embed[eb + t];
    quant[xb + t + 256] = embed[eb + t + 256];
    atomicAdd(&esum[eb + t],       v0);
    atomicAdd(&esum[eb + t + 256], v1);
    if (t == 0) atomicAdd(&bins[k], 1);
}

// ---------------- EMA cluster size + laplace total -------------------------
__global__ void finalize1(const float* __restrict__ cs, const int* __restrict__ bins,
                          float* __restrict__ ncs, float* __restrict__ total_ws) {
    __shared__ float red[16];
    int t = threadIdx.x;
    float s = 0.f;
    for (int k = t; k < Kk; k += 1024) {
        float v = cs[k] * DECAY + OMD * (float)bins[k];
        ncs[k] = v;
        s += v;
    }
    #pragma unroll
    for (int off = 32; off; off >>= 1) s += __shfl_down(s, off);
    if ((t & 63) == 0) red[t >> 6] = s;
    __syncthreads();
    if (t == 0) {
        float tot = 0.f;
        #pragma unroll
        for (int i = 0; i < 16; ++i) tot += red[i];
        total_ws[0] = tot;
    }
}

// ---------------- EMA embed_avg + smoothed divide ---------------------------
__global__ void finalize2(const float* __restrict__ ea, const float* __restrict__ esum,
                          const float* __restrict__ ncs, const float* __restrict__ total_ws,
                          float* __restrict__ nea, float* __restrict__ ne) {
    int idx = blockIdx.x * 256 + threadIdx.x;
    float total = total_ws[0];
    int k = idx >> 7;
    float sm = (ncs[k] + EPS) / (total + Kk * EPS) * total;
    float inv = 1.f / sm;
    float4 a = ((const float4*)ea)[idx];
    float4 s = ((const float4*)esum)[idx];
    float4 r;
    r.x = a.x * DECAY + OMD * s.x;
    r.y = a.y * DECAY + OMD * s.y;
    r.z = a.z * DECAY + OMD * s.z;
    r.w = a.w * DECAY + OMD * s.w;
    ((float4*)nea)[idx] = r;
    float4 e;
    e.x = r.x * inv; e.y = r.y * inv; e.z = r.z * inv; e.w = r.w * inv;
    ((float4*)ne)[idx] = e;
}

extern "C" void kernel_launch(void* const* d_in, const int* in_sizes, int n_in,
                              void* d_out, int out_size, void* d_ws, size_t ws_size,
                              hipStream_t stream) {
    const float* x     = (const float*)d_in[0];
    const float* embed = (const float*)d_in[1];
    const float* cs    = (const float*)d_in[2];
    const float* ea    = (const float*)d_in[3];

    float* out     = (float*)d_out;
    float* o_quant = out;
    float* o_ind   = o_quant + (size_t)Nn * Dd;
    float* o_dist  = o_ind + Nn;
    float* o_ncs   = o_dist + (size_t)Nn * Kk;
    float* o_nea   = o_ncs + Kk;
    float* o_ne    = o_nea + (size_t)Kk * Dd;

    // ---- ws layout (regions sized for 3 planes; padded-ilv uses ~2.1-worth) --
    size_t xp_elems = (size_t)3 * Nn * Dd;       // bf16 capacity (>= Nn*RP)
    size_t ep_elems = (size_t)3 * Kk * Dd;       // >= Kk*RP
    char* w = (char*)d_ws;
    unsigned short* xp = (unsigned short*)w;                 w += xp_elems * 2;
    unsigned short* epp = (unsigned short*)w;                w += ep_elems * 2;
    float* xsq   = (float*)w;                                w += (size_t)Nn * 4;
    float* esq   = (float*)w;                                w += (size_t)Kk * 4;
    int*   ind_i = (int*)w;                                  w += (size_t)Nn * 4;
    int*   bins  = (int*)w;                                  w += (size_t)Kk * 4;
    float* esum  = (float*)w;                                w += (size_t)Kk * Dd * 4;
    unsigned long long* packed = (unsigned long long*)w;     w += (size_t)Nn * 8;
    float* total = (float*)w;                                w += 256;
    size_t need = (size_t)(w - (char*)d_ws);

    if (ws_size >= need) {
        hipMemsetAsync(bins, 0, (size_t)Kk * 4 + (size_t)Kk * Dd * 4 + (size_t)Nn * 8, stream);

        conv_ilv<<<Nn / 4, 256, 0, stream>>>(x, xp, xsq);
        conv_ilv<<<Kk / 4, 256, 0, stream>>>(embed, epp, esq);

        gemm_ilv<<<(Nn / 256) * (Kk / 256), 512, 0, stream>>>(
            xp, epp, xsq, esq, o_dist, packed);

        gather_scatter_packed<<<Nn, 256, 0, stream>>>(
            x, embed, packed, o_quant, o_ind, esum, bins);
    } else {
        float* fxsq  = (float*)d_ws;
        float* fesq  = fxsq + Nn;
        int*   find  = (int*)(fesq + Kk);
        int*   fbins = find + Nn;
        float* fesum = (float*)(fbins + Kk);
        float* ftot  = fesum + (size_t)Kk * Dd;
        xsq = fxsq; esq = fesq; ind_i = find; bins = fbins; esum = fesum; total = ftot;

        hipMemsetAsync(bins, 0, (size_t)(Kk + Kk * Dd) * sizeof(float), stream);
        rows_sq<<<Nn / 4, 256, 0, stream>>>(x, xsq, Nn);
        rows_sq<<<Kk / 4, 256, 0, stream>>>(embed, esq, Kk);
        dim3 g(Nn / BM, Kk / BN);
        gemm_dist<<<g, 256, 0, stream>>>(x, embed, xsq, esq, o_dist);
        argmax_k<<<Nn / 4, 256, 0, stream>>>(o_dist, o_ind, ind_i);
        gather_scatter<<<Nn, 256, 0, stream>>>(x, embed, ind_i, o_quant, esum, bins);
    }

    finalize1<<<1, 1024, 0, stream>>>(cs, bins, o_ncs, total);
    finalize2<<<(Kk * Dd / 4) / 256, 256, 0, stream>>>(ea, esum, o_ncs, total, o_nea, o_ne);
}